// Round 12
// baseline (99.166 us; speedup 1.0000x reference)
//
#include <hip/hip_runtime.h>

#define NUM_CLASSES 80
#define R1 8            // REG_MAX + 1
#define HW 4096         // H*W
#define DPTH 24         // ring depth: channel loads in flight per lane
#define NCH 112         // 80 cls + 32 box channels

// fast hardware transcendentals (outputs are sums of 262K O(1) terms,
// absmax threshold 122.88 -- 2-ulp native math is noise)
__device__ __forceinline__ float fexp(float x) { return __expf(x); }
__device__ __forceinline__ float flog(float x) { return __logf(x); }
__device__ __forceinline__ float frcp(float x) { return __builtin_amdgcn_rcpf(x); }

__device__ __forceinline__ void cls1(float x, float& xm, float& ns) {
    xm = fmaxf(xm, x);
    float e  = fexp(-x);            // exp(-x)
    float s  = frcp(1.0f + e);      // sigmoid
    float sp = x - flog(s);         // softplus(x)
    ns = fmaf(sp * s, s, ns);
}

// one bbox side: softmax-integral corner + DFL term
__device__ __forceinline__ void box8(const float (&xk)[8], float dk,
                                     float& corner, float& dsum) {
    float m = -INFINITY;
    #pragma unroll
    for (int j = 0; j < 8; ++j) m = fmaxf(m, xk[j]);
    float se = 0.0f, swe = 0.0f;
    #pragma unroll
    for (int j = 0; j < 8; ++j) {
        float e = fexp(xk[j] - m);
        se += e;
        swe = fmaf(e, (float)j, swe);
    }
    corner = swe * frcp(se);
    const float lse = m + flog(se);     // logsumexp

    // DFL: runtime bin -> unrolled compare-select (no scratch)
    float d = fminf(fmaxf(dk, 0.0f), (float)(R1 - 1) - 0.1f);
    int tl = (int)d;                    // d >= 0: floor == trunc
    int tr = tl + 1; if (tr > R1 - 1) tr = R1 - 1;
    float x_tl = xk[0], x_tr = xk[0];
    #pragma unroll
    for (int j = 1; j < 8; ++j) {
        if (j == tl) x_tl = xk[j];
        if (j == tr) x_tr = xk[j];
    }
    dsum += (lse - x_tl) * ((float)(tl + 1) - d) + (lse - x_tr) * (d - (float)tl);
}

// 1 thread = 1 anchor. 112 channel loads flow through a DPTH-deep register
// ring: consume channel c, immediately issue channel c+DPTH. Fully unrolled
// so every ring index is compile-time (stays in registers), and the compiler
// emits exact counted s_waitcnt vmcnt(DPTH-1) before each use -- constant
// DPTH loads in flight per wave, no phase drains, no barriers, no LDS merge.
__global__ __launch_bounds__(256)
__attribute__((amdgpu_waves_per_eu(2, 2)))   // 256-VGPR budget: the only setting
                                             // that unpins the allocator from 64
                                             // (R7/R8/R10/R11 vs R3/R4/R6/R9)
void nanodet_loss_kernel(
    const float* __restrict__ anchors,       // [N,4]
    const float* __restrict__ cls_score,     // [B,C,H,W]
    const float* __restrict__ bbox_pred,     // [B,4*R1,H,W]
    const float* __restrict__ label_weights, // [N]
    const float* __restrict__ bbox_targets,  // [N,4]
    const int*   __restrict__ labels,        // [N]
    const int*   __restrict__ nts_p,         // [1]
    const int*   __restrict__ stride_p,      // [1]
    float* __restrict__ out)
{
    const int tid = threadIdx.x;
    const int n   = blockIdx.x * 256 + tid;   // grid sized exactly: no bounds check
    const int b   = n >> 12;                  // n / HW
    const int hw  = n & (HW - 1);             // n % HW

    const float inv_str = frcp((float)stride_p[0]);
    const float inv_nts = frcp((float)nts_p[0]);

    const float* cbase = cls_score + (size_t)b * NUM_CLASSES * HW + hw;
    const float* bbase = bbox_pred + (size_t)b * (4 * R1) * HW + hw;

    // ---- early independent loads (oldest in the vmcnt queue) ----
    const int   lab = labels[n];
    const bool  pos = (lab >= 0) && (lab < NUM_CLASSES);
    const int   lab_c = pos ? lab : 0;
    const float xlab = cbase[(size_t)lab_c * HW];   // label-logit gather
    const float lw   = label_weights[n];
    const float4 a   = ((const float4*)anchors)[n];
    const float4 t   = ((const float4*)bbox_targets)[n];

    const float cx  = 0.5f * (a.x + a.z) * inv_str;
    const float cy  = 0.5f * (a.y + a.w) * inv_str;
    const float tx0 = t.x * inv_str, ty0 = t.y * inv_str;
    const float tx1 = t.z * inv_str, ty1 = t.w * inv_str;
    const float dist[4] = {cx - tx0, cy - ty0, tx1 - cx, ty1 - cy};

    // ---- prologue: fill the ring (DPTH loads in flight) ----
    float ring[DPTH];
    #pragma unroll
    for (int c = 0; c < DPTH; ++c)
        ring[c] = (c < NUM_CLASSES) ? cbase[(size_t)c * HW]
                                    : bbase[(size_t)(c - NUM_CLASSES) * HW];

    // ---- main rolling loop: consume 1, issue 1 ----
    float xm = -INFINITY, ns = 0.0f;
    float xk[8];
    float cor[4];
    float dsum = 0.0f;

    #pragma unroll
    for (int c = 0; c < NCH; ++c) {
        const float x = ring[c % DPTH];
        if (c + DPTH < NCH) {                 // refill the slot just consumed
            ring[(c + DPTH) % DPTH] = (c + DPTH < NUM_CLASSES)
                ? cbase[(size_t)(c + DPTH) * HW]
                : bbase[(size_t)(c + DPTH - NUM_CLASSES) * HW];
        }
        if (c < NUM_CLASSES) {
            cls1(x, xm, ns);
        } else {
            const int j = (c - NUM_CLASSES) & 7;        // compile-time
            xk[j] = x;
            if (j == 7) {
                const int side = (c - NUM_CLASSES) >> 3; // compile-time
                box8(xk, dist[side], cor[side], dsum);
            }
        }
    }

    // ---------------- epilogue (per-lane, R2-proven) ----------------
    const float wt = pos ? frcp(1.0f + fexp(-xm)) : 0.0f;

    const float px0 = cx - cor[0], py0 = cy - cor[1];
    const float px1 = cx + cor[2], py1 = cy + cor[3];

    const float ilx = fmaxf(px0, tx0), ily = fmaxf(py0, ty0);
    const float irx = fminf(px1, tx1), iry = fminf(py1, ty1);
    const float iw = fmaxf(irx - ilx, 0.0f), ih = fmaxf(iry - ily, 0.0f);
    const float overlap = iw * ih;
    const float ap = (px1 - px0) * (py1 - py0);
    const float at = (tx1 - tx0) * (ty1 - ty0);
    const float uni = fmaxf(ap + at - overlap, 1e-6f);
    const float iou = overlap * frcp(uni);

    const float elx = fminf(px0, tx0), ely = fminf(py0, ty0);
    const float erx = fmaxf(px1, tx1), ery = fmaxf(py1, ty1);
    const float ew = fmaxf(erx - elx, 0.0f), eh = fmaxf(ery - ely, 0.0f);
    const float earea = fmaxf(ew * eh, 1e-6f);
    const float giou = iou - (earea - uni) * frcp(earea);

    const float score = pos ? iou : 0.0f;
    float row = ns;
    if (pos) {
        const float e  = fexp(-xlab);
        const float s  = frcp(1.0f + e);     // sigmoid(x_label)
        const float sp = xlab - flog(s);     // softplus(x_label)
        const float negterm = sp * s * s;
        const float sf = score - s;
        const float posl = (sp - xlab * score) * sf * sf;
        row = row - negterm + posl;
    }
    const float qfl = row * lw;

    // ---------------- reduction ----------------
    float v0 = qfl * inv_nts;
    float v1 = (1.0f - giou) * wt * 2.0f;
    float v2 = dsum * wt * 0.0625f;     // 0.25 / 4
    float v3 = wt;

    #pragma unroll
    for (int off = 32; off > 0; off >>= 1) {
        v0 += __shfl_down(v0, off);
        v1 += __shfl_down(v1, off);
        v2 += __shfl_down(v2, off);
        v3 += __shfl_down(v3, off);
    }

    __shared__ float smr[4][4];   // [wave][channel]
    const int w    = tid >> 6;
    const int lane = tid & 63;
    if (lane == 0) {
        smr[w][0] = v0; smr[w][1] = v1;
        smr[w][2] = v2; smr[w][3] = v3;
    }
    __syncthreads();
    if (tid == 0) {
        float s0 = smr[0][0] + smr[1][0] + smr[2][0] + smr[3][0];
        float s1 = smr[0][1] + smr[1][1] + smr[2][1] + smr[3][1];
        float s2 = smr[0][2] + smr[1][2] + smr[2][2] + smr[3][2];
        float s3 = smr[0][3] + smr[1][3] + smr[2][3] + smr[3][3];
        atomicAdd(&out[0], s0);
        atomicAdd(&out[1], s1);
        atomicAdd(&out[2], s2);
        atomicAdd(&out[3], s3);
    }
}

extern "C" void kernel_launch(void* const* d_in, const int* in_sizes, int n_in,
                              void* d_out, int out_size, void* d_ws, size_t ws_size,
                              hipStream_t stream) {
    const float* anchors       = (const float*)d_in[0];
    const float* cls_score     = (const float*)d_in[1];
    const float* bbox_pred     = (const float*)d_in[2];
    const float* label_weights = (const float*)d_in[3];
    const float* bbox_targets  = (const float*)d_in[4];
    const int*   labels        = (const int*)d_in[5];
    const int*   nts_p         = (const int*)d_in[6];
    const int*   stride_p      = (const int*)d_in[7];
    float* out = (float*)d_out;

    const int N = in_sizes[5];  // labels count = B*H*W

    hipMemsetAsync(d_out, 0, 4 * sizeof(float), stream);

    const int block = 256;
    const int grid = N / block;               // 1024 blocks -> 4 waves/SIMD
    nanodet_loss_kernel<<<grid, block, 0, stream>>>(
        anchors, cls_score, bbox_pred, label_weights, bbox_targets,
        labels, nts_p, stride_p, out);
}

// Round 13
// 44.427 us; speedup vs baseline: 2.2321x; 2.2321x over previous
//
#include <hip/hip_runtime.h>

#define NUM_CLASSES 80
#define CPH 40          // cls channels per half
#define R1 8            // REG_MAX + 1
#define HW 4096         // H*W
#define BLOCK 512       // threads per block (2 halves x 256)
#define APB 1024        // anchors per block (4 per thread, float4 loads)

// fast hardware transcendentals (outputs are sums of 262K O(1) terms,
// absmax threshold 122.88 -- 2-ulp native math is noise)
__device__ __forceinline__ float fexp(float x) { return __expf(x); }
__device__ __forceinline__ float flog(float x) { return __logf(x); }
__device__ __forceinline__ float frcp(float x) { return __builtin_amdgcn_rcpf(x); }

// 8 channel-strided float4 loads (16 B/lane = 1 KB/wave-load).
template<int C0>
__device__ __forceinline__ void ld8(float4 (&d)[8], const float* __restrict__ u,
                                    uint32_t e) {
    #pragma unroll
    for (int j = 0; j < 8; ++j)
        d[j] = *reinterpret_cast<const float4*>(u + (uint32_t)((C0 + j) * HW) + e);
}

__device__ __forceinline__ void cls1(float x, float& xm, float& ns) {
    xm = fmaxf(xm, x);
    float e  = fexp(-x);            // exp(-x)
    float s  = frcp(1.0f + e);      // sigmoid
    float sp = x - flog(s);         // softplus(x)
    ns = fmaf(sp * s, s, ns);
}

// 8 channels x 4 anchors (f4 lanes); all indices compile-time
__device__ __forceinline__ void cls8x4(const float4 (&d)[8],
                                       float (&xm)[4], float (&ns)[4]) {
    #pragma unroll
    for (int j = 0; j < 8; ++j) {
        cls1(d[j].x, xm[0], ns[0]);
        cls1(d[j].y, xm[1], ns[1]);
        cls1(d[j].z, xm[2], ns[2]);
        cls1(d[j].w, xm[3], ns[3]);
    }
}

// one bbox side for one anchor: softmax-integral corner + DFL term
__device__ __forceinline__ void box8(const float (&xk)[8], float dk,
                                     float& corner, float& dsum) {
    float m = -INFINITY;
    #pragma unroll
    for (int j = 0; j < 8; ++j) m = fmaxf(m, xk[j]);
    float se = 0.0f, swe = 0.0f;
    #pragma unroll
    for (int j = 0; j < 8; ++j) {
        float e = fexp(xk[j] - m);
        se += e;
        swe = fmaf(e, (float)j, swe);
    }
    corner = swe * frcp(se);
    const float lse = m + flog(se);     // logsumexp

    // DFL: runtime bin -> unrolled compare-select (no scratch)
    float d = fminf(fmaxf(dk, 0.0f), (float)(R1 - 1) - 0.1f);
    int tl = (int)d;                    // d >= 0: floor == trunc
    int tr = tl + 1; if (tr > R1 - 1) tr = R1 - 1;
    float x_tl = xk[0], x_tr = xk[0];
    #pragma unroll
    for (int j = 1; j < 8; ++j) {
        if (j == tl) x_tl = xk[j];
        if (j == tr) x_tr = xk[j];
    }
    dsum += (lse - x_tl) * ((float)(tl + 1) - d) + (lse - x_tr) * (d - (float)tl);
}

// one side (8 channels) for 4 anchors
__device__ __forceinline__ void box8x4(const float4 (&d)[8], const float (&dk)[4],
                                       float (&cor)[4], float (&ds)[4]) {
    float xk[8];
    #pragma unroll
    for (int j = 0; j < 8; ++j) xk[j] = d[j].x;
    box8(xk, dk[0], cor[0], ds[0]);
    #pragma unroll
    for (int j = 0; j < 8; ++j) xk[j] = d[j].y;
    box8(xk, dk[1], cor[1], ds[1]);
    #pragma unroll
    for (int j = 0; j < 8; ++j) xk[j] = d[j].z;
    box8(xk, dk[2], cor[2], ds[2]);
    #pragma unroll
    for (int j = 0; j < 8; ++j) xk[j] = d[j].w;
    box8(xk, dk[3], cor[3], ds[3]);
}

// per-anchor epilogue: GIoU + DFL + QFL contributions
__device__ __forceinline__ void finalize(
    bool pos, float xmax, float negsum, float xlab, float lw,
    float cx, float cy, float tx0, float ty0, float tx1, float ty1,
    float c0, float c1, float c2, float c3, float dsum,
    float& v0, float& v1, float& v2, float& v3)
{
    const float wt = pos ? frcp(1.0f + fexp(-xmax)) : 0.0f;

    const float px0 = cx - c0, py0 = cy - c1;
    const float px1 = cx + c2, py1 = cy + c3;

    const float ilx = fmaxf(px0, tx0), ily = fmaxf(py0, ty0);
    const float irx = fminf(px1, tx1), iry = fminf(py1, ty1);
    const float iw = fmaxf(irx - ilx, 0.0f), ih = fmaxf(iry - ily, 0.0f);
    const float overlap = iw * ih;
    const float ap = (px1 - px0) * (py1 - py0);
    const float at = (tx1 - tx0) * (ty1 - ty0);
    const float uni = fmaxf(ap + at - overlap, 1e-6f);
    const float iou = overlap * frcp(uni);

    const float elx = fminf(px0, tx0), ely = fminf(py0, ty0);
    const float erx = fmaxf(px1, tx1), ery = fmaxf(py1, ty1);
    const float ew = fmaxf(erx - elx, 0.0f), eh = fmaxf(ery - ely, 0.0f);
    const float earea = fmaxf(ew * eh, 1e-6f);
    const float giou = iou - (earea - uni) * frcp(earea);

    const float score = pos ? iou : 0.0f;
    float row = negsum;
    if (pos) {
        const float e  = fexp(-xlab);
        const float s  = frcp(1.0f + e);     // sigmoid(x_label)
        const float sp = xlab - flog(s);     // softplus(x_label)
        const float negterm = sp * s * s;
        const float sf = score - s;
        const float posl = (sp - xlab * score) * sf * sf;
        row = row - negterm + posl;
    }

    v0 += row * lw;                 // qfl (unscaled)
    v1 += (1.0f - giou) * wt;       // bbox (unscaled)
    v2 += dsum * wt;                // dfl (unscaled)
    v3 += wt;
}

__global__ __launch_bounds__(BLOCK)
__attribute__((amdgpu_waves_per_eu(2, 2)))   // 256-VGPR budget: the only setting
                                             // that unpins the allocator from 64
void nanodet_loss_kernel(
    const float* __restrict__ anchors,       // [N,4]
    const float* __restrict__ cls_score,     // [B,C,H,W]
    const float* __restrict__ bbox_pred,     // [B,4*R1,H,W]
    const float* __restrict__ label_weights, // [N]
    const float* __restrict__ bbox_targets,  // [N,4]
    const int*   __restrict__ labels,        // [N]
    const int*   __restrict__ nts_p,         // [1]
    const int*   __restrict__ stride_p,      // [1]
    float* __restrict__ out)
{
    const int tib = threadIdx.x;
    const int h   = tib >> 8;                // half: 0 -> cls 0-39 / sides 0,1
    const int u   = tib & 255;               //       1 -> cls 40-79 / sides 2,3
    const int blk = blockIdx.x;
    const int b   = blk >> 2;                // image (uniform per block)
    const int hw0 = (blk & 3) * APB;         // window start (uniform)
    const int e   = 4 * u;                   // element offset in window
    const int n0  = blk * APB + e;           // first of this thread's 4 anchors

    const float inv_str = frcp((float)stride_p[0]);
    const float inv_nts = frcp((float)nts_p[0]);

    // block-half-uniform bases (SGPR) + per-thread element offset
    const float* cls_h = cls_score + (size_t)b * NUM_CLASSES * HW
                                   + (size_t)(h * CPH) * HW + hw0;
    const float* box_h = bbox_pred + (size_t)b * (4 * R1) * HW
                                   + (size_t)(h * 16) * HW + hw0;
    const uint32_t ue = (uint32_t)e;

    // ---- early independent scalar loads ----
    const int4   lab4 = *(const int4*)(labels + n0);
    const float4 lw4  = *(const float4*)(label_weights + n0);
    float4 a4[4], t4[4];
    #pragma unroll
    for (int i = 0; i < 4; ++i) {
        a4[i] = ((const float4*)anchors)[n0 + i];
        t4[i] = ((const float4*)bbox_targets)[n0 + i];
    }
    int labv[4] = {lab4.x, lab4.y, lab4.z, lab4.w};

    // label-logit gather (this half's channel range, else dummy ch 0)
    float xlab[4];
    #pragma unroll
    for (int i = 0; i < 4; ++i) {
        const int lc = labv[i];
        const bool own = (h == 0) ? (lc >= 0 && lc < CPH)
                                  : (lc >= CPH && lc < NUM_CLASSES);
        const int ch = own ? (lc - h * CPH) : 0;
        xlab[i] = cls_h[(uint32_t)ch * HW + ue + i];
    }

    // ---- register pipeline: THREE 8-channel float4 buffers (depth 2-3:
    //      16-24 wave-loads / 16-24 KB per wave permanently in flight) ----
    float4 A[8], Bb[8], C[8];
    float xm[4] = {-INFINITY, -INFINITY, -INFINITY, -INFINITY};
    float ns[4] = {0.0f, 0.0f, 0.0f, 0.0f};

    ld8<0 >(A,  cls_h, ue);
    ld8<8 >(Bb, cls_h, ue);
    ld8<16>(C,  cls_h, ue);
    cls8x4(A,  xm, ns);  ld8<24>(A,  cls_h, ue);
    cls8x4(Bb, xm, ns);  ld8<32>(Bb, cls_h, ue);
    cls8x4(C,  xm, ns);  ld8<0 >(C,  box_h, ue);   // side 2h
    cls8x4(A,  xm, ns);  ld8<8 >(A,  box_h, ue);   // side 2h+1
    cls8x4(Bb, xm, ns);

    // geometry (covers remaining box load latency)
    float cx[4], cy[4], tx0[4], ty0[4], tx1[4], ty1[4], dk0[4], dk1[4];
    #pragma unroll
    for (int i = 0; i < 4; ++i) {
        cx[i]  = 0.5f * (a4[i].x + a4[i].z) * inv_str;
        cy[i]  = 0.5f * (a4[i].y + a4[i].w) * inv_str;
        tx0[i] = t4[i].x * inv_str; ty0[i] = t4[i].y * inv_str;
        tx1[i] = t4[i].z * inv_str; ty1[i] = t4[i].w * inv_str;
        dk0[i] = (h == 0) ? (cx[i] - tx0[i]) : (tx1[i] - cx[i]);
        dk1[i] = (h == 0) ? (cy[i] - ty0[i]) : (ty1[i] - cy[i]);
    }

    float corA[4], corB[4], ds[4] = {0.0f, 0.0f, 0.0f, 0.0f};
    box8x4(C, dk0, corA, ds);     // side 2h
    box8x4(A, dk1, corB, ds);     // side 2h+1

    // ---- cross-half merge via LDS (SoA float4: conflict-free b128) ----
    __shared__ float4 s_ns[256], s_xm[256], s_xl[256],
                      s_cA[256], s_cB[256], s_ds[256];
    if (h == 1) {
        s_ns[u] = make_float4(ns[0], ns[1], ns[2], ns[3]);
        s_xm[u] = make_float4(xm[0], xm[1], xm[2], xm[3]);
        s_xl[u] = make_float4(xlab[0], xlab[1], xlab[2], xlab[3]);
        s_cA[u] = make_float4(corA[0], corA[1], corA[2], corA[3]);
        s_cB[u] = make_float4(corB[0], corB[1], corB[2], corB[3]);
        s_ds[u] = make_float4(ds[0], ds[1], ds[2], ds[3]);
    }
    __syncthreads();

    float v0 = 0.0f, v1 = 0.0f, v2 = 0.0f, v3 = 0.0f;
    if (h == 0) {
        const float4 q_ns = s_ns[u], q_xm = s_xm[u], q_xl = s_xl[u],
                     q_cA = s_cA[u], q_cB = s_cB[u], q_ds = s_ds[u];
        const float ns1[4] = {q_ns.x, q_ns.y, q_ns.z, q_ns.w};
        const float xm1[4] = {q_xm.x, q_xm.y, q_xm.z, q_xm.w};
        const float xl1[4] = {q_xl.x, q_xl.y, q_xl.z, q_xl.w};
        const float c2a[4] = {q_cA.x, q_cA.y, q_cA.z, q_cA.w};
        const float c3a[4] = {q_cB.x, q_cB.y, q_cB.z, q_cB.w};
        const float ds1[4] = {q_ds.x, q_ds.y, q_ds.z, q_ds.w};
        const float lwv[4] = {lw4.x, lw4.y, lw4.z, lw4.w};

        #pragma unroll
        for (int i = 0; i < 4; ++i) {
            const int lc = labv[i];
            const bool pos = (lc >= 0) && (lc < NUM_CLASSES);
            const float xmax_all = fmaxf(xm[i], xm1[i]);
            const float ns_all   = ns[i] + ns1[i];
            const float xl_sel   = (lc < CPH) ? xlab[i] : xl1[i];
            const float ds_all   = ds[i] + ds1[i];
            finalize(pos, xmax_all, ns_all, xl_sel, lwv[i],
                     cx[i], cy[i], tx0[i], ty0[i], tx1[i], ty1[i],
                     corA[i], corB[i], c2a[i], c3a[i], ds_all,
                     v0, v1, v2, v3);
        }
    }

    v0 *= inv_nts;
    v1 *= 2.0f;
    v2 *= 0.0625f;     // 0.25 / 4

    // ---------------- reduction ----------------
    #pragma unroll
    for (int off = 32; off > 0; off >>= 1) {
        v0 += __shfl_down(v0, off);
        v1 += __shfl_down(v1, off);
        v2 += __shfl_down(v2, off);
        v3 += __shfl_down(v3, off);
    }

    __shared__ float smr[8][4];   // [wave][channel]
    const int w    = tib >> 6;
    const int lane = tib & 63;
    if (lane == 0) {
        smr[w][0] = v0; smr[w][1] = v1;
        smr[w][2] = v2; smr[w][3] = v3;
    }
    __syncthreads();
    if (tib == 0) {
        float s0 = 0.0f, s1 = 0.0f, s2 = 0.0f, s3 = 0.0f;
        #pragma unroll
        for (int i = 0; i < 8; ++i) {
            s0 += smr[i][0]; s1 += smr[i][1];
            s2 += smr[i][2]; s3 += smr[i][3];
        }
        atomicAdd(&out[0], s0);
        atomicAdd(&out[1], s1);
        atomicAdd(&out[2], s2);
        atomicAdd(&out[3], s3);
    }
}

extern "C" void kernel_launch(void* const* d_in, const int* in_sizes, int n_in,
                              void* d_out, int out_size, void* d_ws, size_t ws_size,
                              hipStream_t stream) {
    const float* anchors       = (const float*)d_in[0];
    const float* cls_score     = (const float*)d_in[1];
    const float* bbox_pred     = (const float*)d_in[2];
    const float* label_weights = (const float*)d_in[3];
    const float* bbox_targets  = (const float*)d_in[4];
    const int*   labels        = (const int*)d_in[5];
    const int*   nts_p         = (const int*)d_in[6];
    const int*   stride_p      = (const int*)d_in[7];
    float* out = (float*)d_out;

    const int N = in_sizes[5];  // labels count = B*H*W

    hipMemsetAsync(d_out, 0, 4 * sizeof(float), stream);

    const int grid = N / APB;                 // 256 blocks
    nanodet_loss_kernel<<<grid, BLOCK, 0, stream>>>(
        anchors, cls_score, bbox_pred, label_weights, bbox_targets,
        labels, nts_p, stride_p, out);
}